// Round 6
// baseline (1076.479 us; speedup 1.0000x reference)
//
#include <hip/hip_runtime.h>
#include <hip/hip_bf16.h>

typedef short bf16x8 __attribute__((ext_vector_type(8)));
typedef float f32x16 __attribute__((ext_vector_type(16)));
typedef unsigned short u16;

__device__ __forceinline__ u16 f2bf(float v) {
    union { __hip_bfloat16 h; u16 u; } cv;
    cv.h = __float2bfloat16(v);
    return cv.u;
}

__device__ __forceinline__ void gld_lds16(const u16* g, u16* l) {
    __builtin_amdgcn_global_load_lds(
        (const __attribute__((address_space(1))) void*)g,
        (__attribute__((address_space(3))) void*)l, 16, 0, 0);
}

// ---------------- prep kernels ----------------
__global__ void prep_w1(const float* __restrict__ w, u16* __restrict__ o) {
    int idx = blockIdx.x * 256 + threadIdx.x;
    if (idx >= 25 * 512 * 512) return;
    int ic = idx & 511, rest = idx >> 9;
    int oc = rest & 511, tap = rest >> 9;
    int kh = tap / 5, kw = tap % 5;
    float v = w[(((size_t)oc * 512 + ic) * 5 + kh) * 5 + kw];
    o[idx] = f2bf(v);
}

__global__ void prep_w2(const float* __restrict__ w, u16* __restrict__ o) {
    int idx = blockIdx.x * 256 + threadIdx.x;
    if (idx >= 15 * 512 * 512) return;
    int ic = idx & 511, rest = idx >> 9;
    int oc = rest & 511, tap = rest >> 9;
    int kh = tap / 3, kw = tap % 3;
    float v = w[(((size_t)oc * 512 + ic) * 5 + kh) * 3 + kw];
    o[idx] = f2bf(v);
}

__global__ void prep_bn(const float* __restrict__ g, const float* __restrict__ b,
                        const float* __restrict__ m, const float* __restrict__ v,
                        float* __restrict__ scale, float* __restrict__ shift) {
    int i = blockIdx.x * 256 + threadIdx.x;
    if (i >= 512) return;
    float s = g[i] * rsqrtf(v[i] + 1e-5f);
    scale[i] = s;
    shift[i] = b[i] - m[i] * s;
}

// zero the H-pad rows {0,1,1026,1027} of gathered [8][1028][12][512] bf16
__global__ void zero_gpads(u16* __restrict__ g) {
    int idx = blockIdx.x * 256 + threadIdx.x;   // int4 units
    if (idx >= 8 * 4 * 768) return;             // 768 int4 per (b,row)
    int part = idx % 768;
    int combo = idx / 768;
    int b = combo >> 2, r4 = combo & 3;
    int row = (r4 < 2) ? r4 : (1024 + r4);      // 0,1,1026,1027
    u16* p = g + ((size_t)(b * 1028 + row) * 12 * 512) + (size_t)part * 8;
    *(int4*)p = int4{0, 0, 0, 0};
}

// ---------------- scores + top-k + gather ----------------
__global__ __launch_bounds__(256) void gather_topk(const float* __restrict__ x,
                                                   u16* __restrict__ g) {
    int bt = blockIdx.x;
    int b = bt >> 10, t = bt & 1023;
    const float* xb = x + (size_t)b * 1024 * 512;
    const float* xt = xb + (size_t)t * 512;
    __shared__ float xts[512];
    __shared__ float sc[23];
    __shared__ int sel[12];
    int tid = threadIdx.x;
    for (int i = tid; i < 512; i += 256) xts[i] = xt[i];
    __syncthreads();
    int j0 = t - 11; if (j0 < 0) j0 = 0;
    int j1 = t + 11; if (j1 > 1023) j1 = 1023;
    int C = j1 - j0 + 1;                        // 12..23, always >= 12
    int wave = tid >> 6, lane = tid & 63;
    for (int c = wave; c < C; c += 4) {
        const float* xj = xb + (size_t)(j0 + c) * 512;
        double s = 0.0;
        #pragma unroll
        for (int e = 0; e < 8; ++e) {
            int d = lane * 8 + e;
            s += (double)xj[d] * (double)xts[d];
        }
        #pragma unroll
        for (int off = 32; off; off >>= 1) s += __shfl_xor(s, off, 64);
        if (lane == 0) sc[c] = (float)(s / 22.627416997969522);  // / sqrt(512)
    }
    __syncthreads();
    if (tid == 0) {
        int cnt = 0;
        for (int c = 0; c < C; ++c) {
            float v = sc[c];
            int r = 0;
            for (int k = 0; k < C; ++k) {
                float u = sc[k];
                r += (u > v) || (u == v && k < c);   // stable: lower index wins ties
            }
            if (r < 12) sel[cnt++] = j0 + c;         // ascending j == sorted ids
        }
    }
    __syncthreads();
    u16* dst = g + ((size_t)(b * 1028 + t + 2) * 12) * 512;
    for (int i = tid; i < 12 * 512; i += 256) {
        int s_ = i >> 9, d = i & 511;
        dst[i] = f2bf(xb[(size_t)sel[s_] * 512 + d]);
    }
}

// ---------------- implicit-GEMM conv + bias + BN + ReLU ----------------
// A: [b][outH+KH-1][IN_W][512] bf16 (H zero-padded). Wb: [tap][oc 512][ic 512].
// BARRIER-FREE steady state:
//  - As: one 64-ic chunk, 128B rows, XOR-swizzled (slot s holds chunk s^(r&7)),
//    staged cooperatively via global_load_lds; re-staged every 2 groups with
//    barrier+vmcnt(0)+barrier (7 boundaries/block total).
//  - Ws: WAVE-PRIVATE ring-3 (8 waves x 3 slots x 4KB = 96KB). Each wave DMAs
//    its own 64oc x 32ic slab (64B rows, slot s holds chunk s^((r>>1)&3)),
//    2 bodies ahead; per body just: STAGEW -> s_waitcnt vmcnt(8) -> compute.
//    Only the wave's OWN loads are counted -> no cross-wave sync needed.
//    (wm-partner waves duplicate the fetch; 32KB/body/CU from L2, hidden.)
// Body = (tap, 32-ic half); group = TAPS bodies; NGROUP=16 groups (512 ic).
// MFMA: v_mfma_f32_32x32x16_bf16; wave tile (MF32*32) x 64; 8 waves 2m x 4n.

#define STAGEA(CH) do {                                                       \
    const u16* ga_ = gA + (CH) * 64;                                          \
    _Pragma("unroll 1")                                                       \
    for (int c_ = wv; c_ < ACALL; c_ += 8)                                    \
        gld_lds16(ga_ + (size_t)c_ * 4096 + aoff, &As_l[c_ * 512]);           \
  } while (0)

#define STAGEW(SLOT, TAP2, ICB2) do {                                         \
    const u16* wp_ = Wb + (size_t)(TAP2) * 262144 + wbase + (ICB2);           \
    u16* ldsw_ = &Ws_l[wv][(SLOT)][0];                                        \
    _Pragma("unroll")                                                         \
    for (int i_ = 0; i_ < 4; ++i_)                                            \
        gld_lds16(wp_ + (size_t)i_ * 8192 + woff, ldsw_ + i_ * 512);          \
  } while (0)

#define MFMA_PHASE(TOFF, SR, C4) do {                                         \
    __builtin_amdgcn_s_setprio(1);                                            \
    _Pragma("unroll")                                                         \
    for (int k_ = 0; k_ < 2; ++k_) {                                          \
        bf16x8 afr[MF32], bfr[2];                                             \
        int cw_ = 2 * k_ + kgrp;                                              \
        int cA_ = (C4) + cw_;                                                 \
        _Pragma("unroll")                                                     \
        for (int mf = 0; mf < MF32; ++mf) {                                   \
            int row_ = rowb[mf] + (TOFF);                                     \
            afr[mf] = *(const bf16x8*)&As_l[row_ * 64 +                       \
                          ((cA_ ^ (row_ & 7)) << 3)];                         \
        }                                                                     \
        _Pragma("unroll")                                                     \
        for (int nf = 0; nf < 2; ++nf)                                        \
            bfr[nf] = *(const bf16x8*)&Ws_l[wv][(SR)][rrb[nf] +               \
                          ((cw_ ^ rrs[nf]) << 3)];                            \
        _Pragma("unroll")                                                     \
        for (int mf = 0; mf < MF32; ++mf)                                     \
            _Pragma("unroll")                                                 \
            for (int nf = 0; nf < 2; ++nf)                                    \
                acc[mf][nf] = __builtin_amdgcn_mfma_f32_32x32x16_bf16(        \
                    afr[mf], bfr[nf], acc[mf][nf], 0, 0, 0);                  \
    }                                                                         \
    __builtin_amdgcn_s_setprio(0);                                            \
  } while (0)

template <int IN_W, int LOG_OW, int KH, int KW, int TH, int HTB, int MF32,
          int CPX, bool OCMAJOR>
__global__ __launch_bounds__(512, 1) void conv_bn_relu(
    const u16* __restrict__ A, const u16* __restrict__ Wb,
    const float* __restrict__ bias, const float* __restrict__ bnsc,
    const float* __restrict__ bnsh, void* __restrict__ outp) {
    constexpr int OW = 1 << LOG_OW;
    constexpr int NT = 256;
    constexpr int AROWS = (TH + KH - 1) * IN_W;
    constexpr int ACALL = AROWS / 8;
    constexpr int TAPS = KH * KW;
    constexpr int NGROUP = 16;
    constexpr int OUTH = TH * HTB;
    __shared__ u16 As_l[AROWS * 64];
    __shared__ u16 Ws_l[8][3][2048];       // per-wave 3 slots of 64oc x 32ic

    const int tid = threadIdx.x;
    const int bid = blockIdx.x;
    const int lb = (bid & 7) * CPX + (bid >> 3);   // XCD-chunked swizzle
    const int n0 = (lb & 1) * NT;
    const int mt = lb >> 1;
    const int b = mt / HTB;
    const int h0 = (mt % HTB) * TH;

    const int lane = tid & 63;
    const int wv = tid >> 6;
    const int wm = wv >> 2, wn = wv & 3;
    const int l31 = lane & 31, kgrp = lane >> 5;

    int rowb[MF32];
    #pragma unroll
    for (int mf = 0; mf < MF32; ++mf) {
        int pos = wm * MF32 * 32 + mf * 32 + l31;
        rowb[mf] = (pos >> LOG_OW) * IN_W + (pos & (OW - 1));
    }
    int rrb[2], rrs[2];
    #pragma unroll
    for (int nf = 0; nf < 2; ++nf) {
        int rr = nf * 32 + l31;            // wave-local oc row
        rrb[nf] = rr * 32;
        rrs[nf] = (rr >> 1) & 3;
    }

    // DMA per-lane pre-swizzled global offsets (shorts)
    const int aoff = (lane >> 3) * 512 + (((lane & 7) ^ ((lane >> 3) & 7)) << 3);
    const int woff = (lane >> 2) * 512 + (((lane & 3) ^ ((lane >> 3) & 3)) << 3);
    const size_t wbase = (size_t)(n0 + wn * 64) * 512;

    const size_t abase = ((size_t)b * (OUTH + KH - 1) + h0) * IN_W * 512;
    const u16* gA = A + abase;

    f32x16 acc[MF32][2];
    #pragma unroll
    for (int i = 0; i < MF32; ++i)
        #pragma unroll
        for (int j = 0; j < 2; ++j)
            acc[i][j] = f32x16{0.f,0.f,0.f,0.f,0.f,0.f,0.f,0.f,
                               0.f,0.f,0.f,0.f,0.f,0.f,0.f,0.f};

    // prologue: As chunk 0 + W bodies 0,1 into slots 0,1
    STAGEA(0);
    STAGEW(0, 0, 0);
    STAGEW(1, 1, 0);
    asm volatile("s_waitcnt vmcnt(0)" ::: "memory");
    __builtin_amdgcn_s_barrier();

    int sR = 0, sW = 2;
    #pragma unroll 1
    for (int g = 0; g < NGROUP; ++g) {
        const int c4 = (g & 1) * 4;
        #pragma unroll 1
        for (int t = 0; t < TAPS; ++t) {
            int t2 = t + 2, g2 = g;
            if (t2 >= TAPS) { t2 -= TAPS; g2 = (g + 1) & (NGROUP - 1); }
            STAGEW(sW, t2, g2 * 32);
            asm volatile("s_waitcnt vmcnt(8)" ::: "memory");
            __builtin_amdgcn_sched_barrier(0);
            int kh_ = t / KW;
            int toff_ = kh_ * IN_W + (t - kh_ * KW);
            MFMA_PHASE(toff_, sR, c4);
            sR = sR == 2 ? 0 : sR + 1;
            sW = sW == 2 ? 0 : sW + 1;
        }
        if ((g & 1) && (g + 1 < NGROUP)) {   // As chunk boundary (7 per block)
            __builtin_amdgcn_s_barrier();
            STAGEA((g + 1) >> 1);
            asm volatile("s_waitcnt vmcnt(0)" ::: "memory");
            __builtin_amdgcn_s_barrier();
        }
    }
    asm volatile("s_waitcnt vmcnt(0)" ::: "memory");

    // epilogue: y = relu(conv*sc + (bias*sc + sh))
    // C/D 32x32: col = lane&31, row = (reg&3) + 8*(reg>>2) + 4*(lane>>5)
    #pragma unroll
    for (int nf = 0; nf < 2; ++nf) {
        int oc = n0 + wn * 64 + nf * 32 + l31;
        float scv = bnsc[oc], shv = bnsh[oc], bi = bias[oc];
        float shh = fmaf(bi, scv, shv);
        #pragma unroll
        for (int mf = 0; mf < MF32; ++mf) {
            #pragma unroll
            for (int r = 0; r < 16; ++r) {
                int m = (r & 3) + 8 * (r >> 2) + 4 * kgrp;
                int pos = wm * MF32 * 32 + mf * 32 + m;
                int lh = pos >> LOG_OW, lw = pos & (OW - 1);
                int h = h0 + lh;
                float v = fmaxf(fmaf(acc[mf][nf][r], scv, shh), 0.f);
                if (OCMAJOR) {
                    float* o = (float*)outp;
                    o[(((size_t)b * 512 + oc) * OUTH + h) * OW + lw] = v;
                } else {
                    u16* o = (u16*)outp;
                    o[(((size_t)b * OUTH + h) * OW + lw) * 512 + oc] = f2bf(v);
                }
            }
        }
    }
}

// ---------------- pools ----------------
// in: [8][1024][8][512] bf16 (relu'd, >=0) -> out: [8][516][4][512] bf16, pads zeroed
__global__ void pool1(const u16* __restrict__ in, u16* __restrict__ out) {
    int idx = blockIdx.x * 256 + threadIdx.x;
    if (idx >= 8 * 516 * 4 * 64) return;
    int icv = idx & 63, rest = idx >> 6;
    int w = rest & 3; rest >>= 2;
    int hp = rest % 516, b = rest / 516;
    u16* op = out + (((size_t)(b * 516 + hp) * 4 + w) * 512 + icv * 8);
    if (hp < 2 || hp >= 514) { *(int4*)op = int4{0, 0, 0, 0}; return; }
    int h = (hp - 2) * 2, wi = w * 2;
    const u16* p0 = in + (((size_t)(b * 1024 + h) * 8 + wi) * 512 + icv * 8);
    const u16* a = p0;
    const u16* bq = p0 + 512;
    const u16* c = p0 + 8 * 512;
    const u16* d = p0 + 8 * 512 + 512;
    u16 r[8];
    #pragma unroll
    for (int e = 0; e < 8; ++e) {
        u16 m1 = a[e] > bq[e] ? a[e] : bq[e];     // bf16 >=0: bit pattern monotone
        u16 m2 = c[e] > d[e] ? c[e] : d[e];
        r[e] = m1 > m2 ? m1 : m2;
    }
    *(int4*)op = *(const int4*)r;
}

// in: fp32 [8][512][512][2] (>=0) -> d_out fp32 [8][512][256]
__global__ void pool2(const float* __restrict__ in, float* __restrict__ out) {
    int idx = blockIdx.x * 256 + threadIdx.x;
    if (idx >= 8 * 512 * 256) return;
    const float* p = in + (size_t)idx * 4;
    out[idx] = fmaxf(fmaxf(p[0], p[1]), fmaxf(p[2], p[3]));
}

// ---------------- launch ----------------
extern "C" void kernel_launch(void* const* d_in, const int* in_sizes, int n_in,
                              void* d_out, int out_size, void* d_ws, size_t ws_size,
                              hipStream_t stream) {
    const float* x  = (const float*)d_in[0];
    const float* w1 = (const float*)d_in[1];
    const float* b1 = (const float*)d_in[2];
    const float* g1 = (const float*)d_in[3];
    const float* be1 = (const float*)d_in[4];
    const float* m1 = (const float*)d_in[5];
    const float* v1 = (const float*)d_in[6];
    const float* w2 = (const float*)d_in[7];
    const float* b2 = (const float*)d_in[8];
    const float* g2 = (const float*)d_in[9];
    const float* be2 = (const float*)d_in[10];
    const float* m2 = (const float*)d_in[11];
    const float* v2 = (const float*)d_in[12];
    float* out = (float*)d_out;

    char* ws = (char*)d_ws;
    u16* gathered  = (u16*)(ws);                   // 101,056,512 B
    u16* w1b       = (u16*)(ws + 101056512);       // 13,107,200 B
    u16* w2b       = (u16*)(ws + 114163712);       //  7,864,320 B
    float* bn1s    = (float*)(ws + 122028032);
    float* bn1t    = bn1s + 512;
    float* bn2s    = bn1s + 1024;
    float* bn2t    = bn1s + 1536;
    u16* conv1out  = (u16*)(ws + 122036224);       // 67,108,864 B
    u16* pooled1   = (u16*)(ws);                   // aliases gathered (dead by then)
    float* conv2out = (float*)(ws + 16908288);     // 16,777,216 B (inside gathered region)

    prep_w1<<<(25 * 512 * 512 + 255) / 256, 256, 0, stream>>>(w1, w1b);
    prep_w2<<<(15 * 512 * 512 + 255) / 256, 256, 0, stream>>>(w2, w2b);
    prep_bn<<<2, 256, 0, stream>>>(g1, be1, m1, v1, bn1s, bn1t);
    prep_bn<<<2, 256, 0, stream>>>(g2, be2, m2, v2, bn2s, bn2t);
    zero_gpads<<<(8 * 4 * 768 + 255) / 256, 256, 0, stream>>>(gathered);
    gather_topk<<<8192, 256, 0, stream>>>(x, gathered);

    // conv1: 256pos x 256oc tile, TH=32, MF32=4, grid 8*32*2 = 512, CPX=64
    conv_bn_relu<12, 3, 5, 5, 32, 32, 4, 64, false><<<512, 512, 0, stream>>>(
        gathered, w1b, b1, bn1s, bn1t, conv1out);
    pool1<<<(8 * 516 * 4 * 64 + 255) / 256, 256, 0, stream>>>(conv1out, pooled1);
    // conv2: 64pos x 256oc tile, TH=32, MF32=1, grid 8*16*2 = 256, CPX=32
    conv_bn_relu<4, 1, 5, 3, 32, 16, 1, 32, true><<<256, 512, 0, stream>>>(
        pooled1, w2b, b2, bn2s, bn2t, conv2out);
    pool2<<<(8 * 512 * 256 + 255) / 256, 256, 0, stream>>>(conv2out, out);
}

// Round 7
// 923.037 us; speedup vs baseline: 1.1662x; 1.1662x over previous
//
#include <hip/hip_runtime.h>
#include <hip/hip_bf16.h>

typedef short bf16x8 __attribute__((ext_vector_type(8)));
typedef float f32x16 __attribute__((ext_vector_type(16)));
typedef unsigned short u16;

__device__ __forceinline__ u16 f2bf(float v) {
    union { __hip_bfloat16 h; u16 u; } cv;
    cv.h = __float2bfloat16(v);
    return cv.u;
}

__device__ __forceinline__ void gld_lds16(const u16* g, u16* l) {
    __builtin_amdgcn_global_load_lds(
        (const __attribute__((address_space(1))) void*)g,
        (__attribute__((address_space(3))) void*)l, 16, 0, 0);
}

// ---------------- prep kernels ----------------
// Wt layout: [T][ocs(8)][c(4)][ocl(64)][e(8)]  with T = (ic>>5)*TAPS + tap
__global__ void prep_w1(const float* __restrict__ w, u16* __restrict__ o) {
    int idx = blockIdx.x * 256 + threadIdx.x;
    if (idx >= 25 * 512 * 512) return;
    int e = idx & 7, ocl = (idx >> 3) & 63, c = (idx >> 9) & 3;
    int ocs = (idx >> 11) & 7, T = idx >> 14;
    int icb = T / 25, tap = T - icb * 25;
    int ic = icb * 32 + c * 8 + e;
    int oc = ocs * 64 + ocl;
    int kh = tap / 5, kw = tap - kh * 5;
    o[idx] = f2bf(w[(((size_t)oc * 512 + ic) * 5 + kh) * 5 + kw]);
}

__global__ void prep_w2(const float* __restrict__ w, u16* __restrict__ o) {
    int idx = blockIdx.x * 256 + threadIdx.x;
    if (idx >= 15 * 512 * 512) return;
    int e = idx & 7, ocl = (idx >> 3) & 63, c = (idx >> 9) & 3;
    int ocs = (idx >> 11) & 7, T = idx >> 14;
    int icb = T / 15, tap = T - icb * 15;
    int ic = icb * 32 + c * 8 + e;
    int oc = ocs * 64 + ocl;
    int kh = tap / 3, kw = tap - kh * 3;
    o[idx] = f2bf(w[(((size_t)oc * 512 + ic) * 5 + kh) * 3 + kw]);
}

__global__ void prep_bn(const float* __restrict__ g, const float* __restrict__ b,
                        const float* __restrict__ m, const float* __restrict__ v,
                        float* __restrict__ scale, float* __restrict__ shift) {
    int i = blockIdx.x * 256 + threadIdx.x;
    if (i >= 512) return;
    float s = g[i] * rsqrtf(v[i] + 1e-5f);
    scale[i] = s;
    shift[i] = b[i] - m[i] * s;
}

// zero pads: gathered [b][cc64][row 12336][8] rows h in {0,1,1026,1027} (x12 w)
//            pooled1  [b][cc64][row 2064][8] rows hp in {0,1,514,515} (x4 w)
__global__ void zero_pads(u16* __restrict__ gath, u16* __restrict__ pooled) {
    int idx = blockIdx.x * 256 + threadIdx.x;
    if (idx < 24576) {
        int w = idx % 12, r = idx / 12;
        int h4 = r & 3; r >>= 2;
        int cc = r & 63, b = r >> 6;
        int h = (h4 < 2) ? h4 : 1024 + h4;        // 0,1,1026,1027
        *(int4*)&gath[(((size_t)(b * 64 + cc)) * 12336 + h * 12 + w) * 8] =
            int4{0, 0, 0, 0};
    } else if (idx < 24576 + 8192) {
        int j = idx - 24576;
        int w = j & 3, r = j >> 2;
        int h4 = r & 3; r >>= 2;
        int cc = r & 63, b = r >> 6;
        int hp = (h4 < 2) ? h4 : 512 + h4;        // 0,1,514,515
        *(int4*)&pooled[(((size_t)(b * 64 + cc)) * 2064 + hp * 4 + w) * 8] =
            int4{0, 0, 0, 0};
    }
}

// ---------------- scores + top-k + gather ----------------
// writes gathered[b][cc(64)][row = (t+2)*12 + s][8 ic] bf16
__global__ __launch_bounds__(256) void gather_topk(const float* __restrict__ x,
                                                   u16* __restrict__ g) {
    int bt = blockIdx.x;
    int b = bt >> 10, t = bt & 1023;
    const float* xb = x + (size_t)b * 1024 * 512;
    const float* xt = xb + (size_t)t * 512;
    __shared__ float xts[512];
    __shared__ float sc[23];
    __shared__ int sel[12];
    int tid = threadIdx.x;
    for (int i = tid; i < 512; i += 256) xts[i] = xt[i];
    __syncthreads();
    int j0 = t - 11; if (j0 < 0) j0 = 0;
    int j1 = t + 11; if (j1 > 1023) j1 = 1023;
    int C = j1 - j0 + 1;                        // 12..23, always >= 12
    int wave = tid >> 6, lane = tid & 63;
    for (int c = wave; c < C; c += 4) {
        const float* xj = xb + (size_t)(j0 + c) * 512;
        double s = 0.0;
        #pragma unroll
        for (int e = 0; e < 8; ++e) {
            int d = lane * 8 + e;
            s += (double)xj[d] * (double)xts[d];
        }
        #pragma unroll
        for (int off = 32; off; off >>= 1) s += __shfl_xor(s, off, 64);
        if (lane == 0) sc[c] = (float)(s / 22.627416997969522);  // / sqrt(512)
    }
    __syncthreads();
    if (tid == 0) {
        int cnt = 0;
        for (int c = 0; c < C; ++c) {
            float v = sc[c];
            int r = 0;
            for (int k = 0; k < C; ++k) {
                float u = sc[k];
                r += (u > v) || (u == v && k < c);   // stable: lower index wins
            }
            if (r < 12) sel[cnt++] = j0 + c;         // ascending j == sorted ids
        }
    }
    __syncthreads();
    const size_t rowbase = (size_t)(t + 2) * 12;
    for (int i = tid; i < 768; i += 256) {           // 64 cc x 12 s blocks
        int cc = i / 12, s = i - cc * 12;
        const float* src = xb + (size_t)sel[s] * 512 + cc * 8;
        float4 f0 = *(const float4*)src;
        float4 f1 = *(const float4*)(src + 4);
        u16 pk[8] = {f2bf(f0.x), f2bf(f0.y), f2bf(f0.z), f2bf(f0.w),
                     f2bf(f1.x), f2bf(f1.y), f2bf(f1.z), f2bf(f1.w)};
        *(int4*)&g[(((size_t)(b * 64 + cc)) * 12336 + rowbase + s) * 8] =
            *(const int4*)pk;
    }
}

// ---------------- implicit-GEMM conv + bias + BN + ReLU + fused 2x2 pool ----
// A: [b][cc(64)][row(PLANE)][8] bf16, rows H-zero-padded by 2.
// Wt: [T][ocs(8)][c(4)][ocl(64)][8] bf16, T = icb32*TAPS + tap (body-linear).
// LDS A: [c8(8)][row(ARP)][16B]  (chunk-major: wave b128 reads = 2x512B
//   contiguous -> conflict-free, zero VALU: base reg + imm).
// LDS W: per-wave ring-2 [wv][slot(2)][c(4)][ocl(64)][16B]; prefetch dist 1,
//   wave-private vmcnt(4) -> NO cross-wave sync for W. Barriers only at the
//   7 A-chunk boundaries.
// MFMA 32x32x16; 8 waves 2m x 4n; wave tile (MF32*32) x 64.
// Epilogue fuses the 2x2 maxpool (quad lives in one lane's C regs).

template <int IN_W, int LOG_OW, int KH, int KW, int TH, int HTB, int MF32,
          int ARP, int PLANE, int CPX, bool POOL2E>
__global__ __launch_bounds__(512, 1) void conv_fused(
    const u16* __restrict__ A, const u16* __restrict__ Wt,
    const float* __restrict__ bias, const float* __restrict__ bnsc,
    const float* __restrict__ bnsh, void* __restrict__ outp) {
    constexpr int OW = 1 << LOG_OW;
    constexpr int TAPS = KH * KW;
    constexpr int JC = ARP / 64;
    constexpr int MFR = (32 >> LOG_OW) * IN_W;   // A-row advance per mf
    __shared__ u16 As_l[8 * ARP * 8];
    __shared__ u16 Ws_l[8][2][2048];

    const int tid = threadIdx.x;
    const int bid = blockIdx.x;
    const int lb = (bid & 7) * CPX + (bid >> 3);   // XCD-chunked swizzle
    const int n0 = (lb & 1) * 256;
    const int mt = lb >> 1;
    const int b = mt / HTB;
    const int h0 = (mt % HTB) * TH;

    const int lane = tid & 63;
    const int wv = tid >> 6;
    const int wm = wv >> 2, wn = wv & 3;
    const int l31 = lane & 31, kgrp = lane >> 5;

    const int pos0 = wm * MF32 * 32 + l31;
    const int rowb0 = (pos0 >> LOG_OW) * IN_W + (pos0 & (OW - 1));
    const u16* aB = &As_l[(kgrp * ARP + rowb0) * 8];

    const int wlo = kgrp * 512 + l31 * 8;
    const u16* wA0 = &Ws_l[wv][0][wlo];
    const u16* wB0 = &Ws_l[wv][1][wlo];
    u16* dA = &Ws_l[wv][0][0];
    u16* dB = &Ws_l[wv][1][0];

    const int ocs = (lb & 1) * 4 + wn;
    const u16* wsg = Wt + (size_t)(8 + ocs) * 2048 + lane * 8;   // T=1 base
    const u16* wprol = Wt + (size_t)ocs * 2048 + lane * 8;       // T=0

    const u16* gAh = A + (((size_t)b * 64) * PLANE + h0 * IN_W + lane) * 8;

    f32x16 acc[MF32][2];
    #pragma unroll
    for (int i = 0; i < MF32; ++i)
        #pragma unroll
        for (int j = 0; j < 2; ++j)
            acc[i][j] = f32x16{0.f,0.f,0.f,0.f,0.f,0.f,0.f,0.f,
                               0.f,0.f,0.f,0.f,0.f,0.f,0.f,0.f};

    // prologue: A chunk 0 + W body T=0 -> slot0
    #pragma unroll 1
    for (int q = wv; q < 8 * JC; q += 8) {
        int c8 = q / JC, j = q - c8 * JC;
        gld_lds16(gAh + ((size_t)(c8 * PLANE) + j * 64) * 8,
                  &As_l[(c8 * ARP + j * 64) * 8]);
    }
    #pragma unroll
    for (int c = 0; c < 4; ++c)
        gld_lds16(wprol + c * 512, dA + c * 512);
    asm volatile("s_waitcnt vmcnt(0)" ::: "memory");
    __builtin_amdgcn_s_barrier();

    #pragma unroll 1
    for (int g = 0; g < 16; ++g) {
        const u16* wRe = (g & 1) ? wB0 : wA0;   // body t even reads slot g&1
        const u16* wRo = (g & 1) ? wA0 : wB0;
        u16* dE = (g & 1) ? dA : dB;            // t even stages slot !(g&1)
        u16* dO = (g & 1) ? dB : dA;
        const u16* aR = aB + (g & 1) * (4 * ARP * 8);
        #pragma unroll
        for (int t = 0; t < TAPS; ++t) {
            const u16* wS = wsg + (size_t)t * 16384;   // stage body T+1
            u16* dS = (t & 1) ? dO : dE;
            #pragma unroll
            for (int c = 0; c < 4; ++c)
                gld_lds16(wS + c * 512, dS + c * 512);
            asm volatile("s_waitcnt vmcnt(4)" ::: "memory");
            __builtin_amdgcn_sched_barrier(0);
            const int kh_ = t / KW;
            const int toff = kh_ * IN_W + (t - kh_ * KW);
            const u16* wR = (t & 1) ? wRo : wRe;
            __builtin_amdgcn_s_setprio(1);
            #pragma unroll
            for (int k = 0; k < 2; ++k) {
                bf16x8 afr[MF32], bfr[2];
                #pragma unroll
                for (int mf = 0; mf < MF32; ++mf)
                    afr[mf] = *(const bf16x8*)(aR +
                        (toff + MFR * mf + 2 * k * ARP) * 8);
                #pragma unroll
                for (int nf = 0; nf < 2; ++nf)
                    bfr[nf] = *(const bf16x8*)(wR + k * 1024 + nf * 256);
                #pragma unroll
                for (int mf = 0; mf < MF32; ++mf)
                    #pragma unroll
                    for (int nf = 0; nf < 2; ++nf)
                        acc[mf][nf] = __builtin_amdgcn_mfma_f32_32x32x16_bf16(
                            afr[mf], bfr[nf], acc[mf][nf], 0, 0, 0);
            }
            __builtin_amdgcn_s_setprio(0);
        }
        wsg += (size_t)TAPS * 16384;
        if ((g & 1) && g < 15) {                 // A chunk boundary (7x)
            __builtin_amdgcn_s_barrier();
            const int chn = (g + 1) >> 1;
            #pragma unroll 1
            for (int q = wv; q < 8 * JC; q += 8) {
                int c8 = q / JC, j = q - c8 * JC;
                gld_lds16(gAh + ((size_t)((chn * 8 + c8) * PLANE) + j * 64) * 8,
                          &As_l[(c8 * ARP + j * 64) * 8]);
            }
            asm volatile("s_waitcnt vmcnt(0)" ::: "memory");
            __builtin_amdgcn_s_barrier();
        }
    }
    asm volatile("s_waitcnt vmcnt(0)" ::: "memory");

    // epilogue: y = relu(max4(conv)*sc + (bias*sc + sh)), fused 2x2 pool.
    // C/D 32x32: col = lane&31, row = (r&3) + 8*(r>>2) + 4*(lane>>5)
    #pragma unroll
    for (int nf = 0; nf < 2; ++nf) {
        const int oc = n0 + wn * 64 + nf * 32 + l31;
        const float scv = bnsc[oc], shv = bnsh[oc], bi = bias[oc];
        const float shh = fmaf(bi, scv, shv);
        #pragma unroll
        for (int mf = 0; mf < MF32; ++mf) {
            #pragma unroll
            for (int q = 0; q < 4; ++q) {
                if (!POOL2E) {
                    // quad {r0,r0+1,r0+4,r0+5}: w-pair (+1 row) x h-pair (+8)
                    const int r0 = (q & 1) * 2 + (q >> 1) * 8;   // 0,2,8,10
                    float mx = fmaxf(
                        fmaxf(acc[mf][nf][r0], acc[mf][nf][r0 + 1]),
                        fmaxf(acc[mf][nf][r0 + 4], acc[mf][nf][r0 + 5]));
                    float v = fmaxf(fmaf(mx, scv, shh), 0.f);
                    const int row0 = (r0 & 3) + 8 * (r0 >> 2) + 4 * kgrp;
                    const int pos = wm * MF32 * 32 + mf * 32 + row0;
                    const int h = h0 + (pos >> LOG_OW);
                    const int w = pos & (OW - 1);
                    const int prow = (2 + (h >> 1)) * 4 + (w >> 1);
                    u16* o = (u16*)outp;
                    o[(((size_t)(b * 64 + (oc >> 3))) * 2064 + prow) * 8 +
                      (oc & 7)] = f2bf(v);
                } else {
                    // quad {r0..r0+3}: 4 consecutive positions (h-pair x w-pair)
                    const int r0 = q * 4;
                    float mx = fmaxf(
                        fmaxf(acc[mf][nf][r0], acc[mf][nf][r0 + 1]),
                        fmaxf(acc[mf][nf][r0 + 2], acc[mf][nf][r0 + 3]));
                    float v = fmaxf(fmaf(mx, scv, shh), 0.f);
                    const int row0 = 8 * (r0 >> 2) + 4 * kgrp;
                    const int pos = wm * 32 + row0;
                    const int pout = (h0 + (pos >> 1)) >> 1;
                    float* o = (float*)outp;
                    o[((size_t)(b * 512 + oc)) * 256 + pout] = v;
                }
            }
        }
    }
}

// ---------------- launch ----------------
extern "C" void kernel_launch(void* const* d_in, const int* in_sizes, int n_in,
                              void* d_out, int out_size, void* d_ws, size_t ws_size,
                              hipStream_t stream) {
    const float* x  = (const float*)d_in[0];
    const float* w1 = (const float*)d_in[1];
    const float* b1 = (const float*)d_in[2];
    const float* g1 = (const float*)d_in[3];
    const float* be1 = (const float*)d_in[4];
    const float* m1 = (const float*)d_in[5];
    const float* v1 = (const float*)d_in[6];
    const float* w2 = (const float*)d_in[7];
    const float* b2 = (const float*)d_in[8];
    const float* g2 = (const float*)d_in[9];
    const float* be2 = (const float*)d_in[10];
    const float* m2 = (const float*)d_in[11];
    const float* v2 = (const float*)d_in[12];
    float* out = (float*)d_out;

    char* ws = (char*)d_ws;
    u16* gathered = (u16*)(ws);                    // 101,056,512 B
    u16* w1t      = (u16*)(ws + 101056512);        // 13,107,200 B
    u16* w2t      = (u16*)(ws + 114163712);        //  7,864,320 B
    float* bn1s   = (float*)(ws + 122028032);
    float* bn1t   = bn1s + 512;
    float* bn2s   = bn1s + 1024;
    float* bn2t   = bn1s + 1536;
    u16* pooled1  = (u16*)(ws + 122036224);        // 16,908,288 B

    prep_w1<<<25600, 256, 0, stream>>>(w1, w1t);
    prep_w2<<<15360, 256, 0, stream>>>(w2, w2t);
    prep_bn<<<2, 256, 0, stream>>>(g1, be1, m1, v1, bn1s, bn1t);
    prep_bn<<<2, 256, 0, stream>>>(g2, be2, m2, v2, bn2s, bn2t);
    zero_pads<<<128, 256, 0, stream>>>(gathered, pooled1);
    gather_topk<<<8192, 256, 0, stream>>>(x, gathered);

    // conv1+pool1: 256pos x 256oc tile, TH=32, ARP=448, PLANE=12336
    conv_fused<12, 3, 5, 5, 32, 32, 4, 448, 12336, 64, false>
        <<<512, 512, 0, stream>>>(gathered, w1t, b1, bn1s, bn1t, pooled1);
    // conv2+pool2: 64pos x 256oc tile, TH=32, ARP=192, PLANE=2064 -> d_out
    conv_fused<4, 1, 5, 3, 32, 16, 1, 192, 2064, 32, true>
        <<<256, 512, 0, stream>>>(pooled1, w2t, b2, bn2s, bn2t, out);
}

// Round 8
// 888.087 us; speedup vs baseline: 1.2121x; 1.0394x over previous
//
#include <hip/hip_runtime.h>
#include <hip/hip_bf16.h>

typedef short bf16x8 __attribute__((ext_vector_type(8)));
typedef float f32x16 __attribute__((ext_vector_type(16)));
typedef unsigned short u16;

__device__ __forceinline__ u16 f2bf(float v) {
    union { __hip_bfloat16 h; u16 u; } cv;
    cv.h = __float2bfloat16(v);
    return cv.u;
}

__device__ __forceinline__ void gld_lds16(const u16* g, u16* l) {
    __builtin_amdgcn_global_load_lds(
        (const __attribute__((address_space(1))) void*)g,
        (__attribute__((address_space(3))) void*)l, 16, 0, 0);
}

// ---------------- prep kernels ----------------
// Wt layout: [T][ocs(8)][c(4)][ocl(64)][e(8)]  with T = (ic>>5)*TAPS + tap
__global__ void prep_w1(const float* __restrict__ w, u16* __restrict__ o) {
    int idx = blockIdx.x * 256 + threadIdx.x;
    if (idx >= 25 * 512 * 512) return;
    int e = idx & 7, ocl = (idx >> 3) & 63, c = (idx >> 9) & 3;
    int ocs = (idx >> 11) & 7, T = idx >> 14;
    int icb = T / 25, tap = T - icb * 25;
    int ic = icb * 32 + c * 8 + e;
    int oc = ocs * 64 + ocl;
    int kh = tap / 5, kw = tap - kh * 5;
    o[idx] = f2bf(w[(((size_t)oc * 512 + ic) * 5 + kh) * 5 + kw]);
}

__global__ void prep_w2(const float* __restrict__ w, u16* __restrict__ o) {
    int idx = blockIdx.x * 256 + threadIdx.x;
    if (idx >= 15 * 512 * 512) return;
    int e = idx & 7, ocl = (idx >> 3) & 63, c = (idx >> 9) & 3;
    int ocs = (idx >> 11) & 7, T = idx >> 14;
    int icb = T / 15, tap = T - icb * 15;
    int ic = icb * 32 + c * 8 + e;
    int oc = ocs * 64 + ocl;
    int kh = tap / 3, kw = tap - kh * 3;
    o[idx] = f2bf(w[(((size_t)oc * 512 + ic) * 5 + kh) * 3 + kw]);
}

__global__ void prep_bn(const float* __restrict__ g, const float* __restrict__ b,
                        const float* __restrict__ m, const float* __restrict__ v,
                        float* __restrict__ scale, float* __restrict__ shift) {
    int i = blockIdx.x * 256 + threadIdx.x;
    if (i >= 512) return;
    float s = g[i] * rsqrtf(v[i] + 1e-5f);
    scale[i] = s;
    shift[i] = b[i] - m[i] * s;
}

// zero pads: gathered [b][cc64][row 12336][8] rows h in {0,1,1026,1027} (x12 w)
//            pooled1  [b][cc64][row 2064][8] rows hp in {0,1,514,515} (x4 w)
__global__ void zero_pads(u16* __restrict__ gath, u16* __restrict__ pooled) {
    int idx = blockIdx.x * 256 + threadIdx.x;
    if (idx < 24576) {
        int w = idx % 12, r = idx / 12;
        int h4 = r & 3; r >>= 2;
        int cc = r & 63, b = r >> 6;
        int h = (h4 < 2) ? h4 : 1024 + h4;        // 0,1,1026,1027
        *(int4*)&gath[(((size_t)(b * 64 + cc)) * 12336 + h * 12 + w) * 8] =
            int4{0, 0, 0, 0};
    } else if (idx < 24576 + 8192) {
        int j = idx - 24576;
        int w = j & 3, r = j >> 2;
        int h4 = r & 3; r >>= 2;
        int cc = r & 63, b = r >> 6;
        int hp = (h4 < 2) ? h4 : 512 + h4;        // 0,1,514,515
        *(int4*)&pooled[(((size_t)(b * 64 + cc)) * 2064 + hp * 4 + w) * 8] =
            int4{0, 0, 0, 0};
    }
}

// ---------------- scores + top-k + gather ----------------
// writes gathered[b][cc(64)][row = (t+2)*12 + s][8 ic] bf16
__global__ __launch_bounds__(256) void gather_topk(const float* __restrict__ x,
                                                   u16* __restrict__ g) {
    int bt = blockIdx.x;
    int b = bt >> 10, t = bt & 1023;
    const float* xb = x + (size_t)b * 1024 * 512;
    const float* xt = xb + (size_t)t * 512;
    __shared__ float xts[512];
    __shared__ float sc[23];
    __shared__ int sel[12];
    int tid = threadIdx.x;
    for (int i = tid; i < 512; i += 256) xts[i] = xt[i];
    __syncthreads();
    int j0 = t - 11; if (j0 < 0) j0 = 0;
    int j1 = t + 11; if (j1 > 1023) j1 = 1023;
    int C = j1 - j0 + 1;                        // 12..23, always >= 12
    int wave = tid >> 6, lane = tid & 63;
    for (int c = wave; c < C; c += 4) {
        const float* xj = xb + (size_t)(j0 + c) * 512;
        double s = 0.0;
        #pragma unroll
        for (int e = 0; e < 8; ++e) {
            int d = lane * 8 + e;
            s += (double)xj[d] * (double)xts[d];
        }
        #pragma unroll
        for (int off = 32; off; off >>= 1) s += __shfl_xor(s, off, 64);
        if (lane == 0) sc[c] = (float)(s / 22.627416997969522);  // / sqrt(512)
    }
    __syncthreads();
    if (tid == 0) {
        int cnt = 0;
        for (int c = 0; c < C; ++c) {
            float v = sc[c];
            int r = 0;
            for (int k = 0; k < C; ++k) {
                float u = sc[k];
                r += (u > v) || (u == v && k < c);   // stable: lower index wins
            }
            if (r < 12) sel[cnt++] = j0 + c;         // ascending j == sorted ids
        }
    }
    __syncthreads();
    const size_t rowbase = (size_t)(t + 2) * 12;
    for (int i = tid; i < 768; i += 256) {           // 64 cc x 12 s blocks
        int cc = i / 12, s = i - cc * 12;
        const float* src = xb + (size_t)sel[s] * 512 + cc * 8;
        float4 f0 = *(const float4*)src;
        float4 f1 = *(const float4*)(src + 4);
        u16 pk[8] = {f2bf(f0.x), f2bf(f0.y), f2bf(f0.z), f2bf(f0.w),
                     f2bf(f1.x), f2bf(f1.y), f2bf(f1.z), f2bf(f1.w)};
        *(int4*)&g[(((size_t)(b * 64 + cc)) * 12336 + rowbase + s) * 8] =
            *(const int4*)pk;
    }
}

// ---------------- implicit-GEMM conv + bias + BN + ReLU + fused 2x2 pool ----
// A: [b][cc(64)][row(PLANE)][8] bf16, rows H-zero-padded by 2.
// Wt: [T][ocs(8)][c(4)][ocl(64)][8] bf16, T = icb32*TAPS + tap (body-linear).
// LDS holds ONLY A: 8 ic8-slabs of ARP rows x 16B, slab stride padded +64B.
//   Wave b128 A-read = 2 contiguous 512B blocks -> conflict-free, base+imm.
// W goes GLOBAL->VGPR: per body each wave loads its 4 B-frags (dwordx4 from
//   L2), double-buffered one body ahead; compiler inserts the counted vmcnt.
//   No W in LDS -> LDS reads/body drop 12->8 per wave, LDS=57.9KB -> 2 blk/CU.
// Barriers only at the 7 A-chunk boundaries.
// MFMA 32x32x16; 8 waves 2m x 4n; wave tile (MF32*32) x 64.
// Epilogue fuses the 2x2 maxpool (quad lives in one lane's C regs).

template <int IN_W, int LOG_OW, int KH, int KW, int TH, int HTB, int MF32,
          int ARP, int PLANE, int CPX, bool POOL2E>
__global__ __launch_bounds__(512, 1) void conv_fused(
    const u16* __restrict__ A, const u16* __restrict__ Wt,
    const float* __restrict__ bias, const float* __restrict__ bnsc,
    const float* __restrict__ bnsh, void* __restrict__ outp) {
    constexpr int OW = 1 << LOG_OW;
    constexpr int TAPS = KH * KW;
    constexpr int JC = ARP / 64;
    constexpr int MFR = (32 >> LOG_OW) * IN_W;   // A-row advance per mf
    constexpr int SLAB = ARP * 8 + 32;           // shorts; +64B pad per slab
    __shared__ u16 As_l[8 * SLAB];

    const int tid = threadIdx.x;
    const int bid = blockIdx.x;
    const int lb = (bid & 7) * CPX + (bid >> 3);   // XCD-chunked swizzle
    const int n0 = (lb & 1) * 256;
    const int mt = lb >> 1;
    const int b = mt / HTB;
    const int h0 = (mt % HTB) * TH;

    const int lane = tid & 63;
    const int wv = tid >> 6;
    const int wm = wv >> 2, wn = wv & 3;
    const int l31 = lane & 31, kgrp = lane >> 5;

    const int pos0 = wm * MF32 * 32 + l31;
    const int rowb0 = (pos0 >> LOG_OW) * IN_W + (pos0 & (OW - 1));
    const u16* aB = &As_l[kgrp * SLAB + rowb0 * 8];

    const int ocs = (lb & 1) * 4 + wn;
    // per-lane W base (T=0): [ocs][c = kgrp][ocl = l31][8]
    const u16* wlane = Wt + (size_t)ocs * 2048 + kgrp * 512 + l31 * 8;

    const u16* gAh = A + (((size_t)b * 64) * PLANE + h0 * IN_W + lane) * 8;

    f32x16 acc[MF32][2];
    #pragma unroll
    for (int i = 0; i < MF32; ++i)
        #pragma unroll
        for (int j = 0; j < 2; ++j)
            acc[i][j] = f32x16{0.f,0.f,0.f,0.f,0.f,0.f,0.f,0.f,
                               0.f,0.f,0.f,0.f,0.f,0.f,0.f,0.f};

    // prologue: A chunk 0 (DMA) + W body T=0 into regs
    #pragma unroll 1
    for (int q = wv; q < 8 * JC; q += 8) {
        int c8 = q / JC, j = q - c8 * JC;
        gld_lds16(gAh + ((size_t)(c8 * PLANE) + j * 64) * 8,
                  &As_l[c8 * SLAB + j * 512]);
    }
    bf16x8 wc0 = *(const bf16x8*)(wlane);          // (k0,nf0)
    bf16x8 wc1 = *(const bf16x8*)(wlane + 256);    // (k0,nf1)
    bf16x8 wc2 = *(const bf16x8*)(wlane + 1024);   // (k1,nf0)
    bf16x8 wc3 = *(const bf16x8*)(wlane + 1280);   // (k1,nf1)
    asm volatile("s_waitcnt vmcnt(0)" ::: "memory");
    __builtin_amdgcn_s_barrier();

    const u16* wsg = wlane + 16384;                // T=1 base

    #pragma unroll 1
    for (int g = 0; g < 16; ++g) {
        const u16* aR = (g & 1) ? aB + 4 * SLAB : aB;
        #pragma unroll
        for (int t = 0; t < TAPS; ++t) {
            const u16* wS = wsg + (size_t)t * 16384;   // prefetch body T+1
            bf16x8 wn0 = *(const bf16x8*)(wS);
            bf16x8 wn1 = *(const bf16x8*)(wS + 256);
            bf16x8 wn2 = *(const bf16x8*)(wS + 1024);
            bf16x8 wn3 = *(const bf16x8*)(wS + 1280);
            const int kh_ = t / KW;
            const int toff = kh_ * IN_W + (t - kh_ * KW);
            __builtin_amdgcn_s_setprio(1);
            bf16x8 afr[MF32];
            #pragma unroll
            for (int mf = 0; mf < MF32; ++mf)
                afr[mf] = *(const bf16x8*)(aR + (toff + MFR * mf) * 8);
            #pragma unroll
            for (int mf = 0; mf < MF32; ++mf) {
                acc[mf][0] = __builtin_amdgcn_mfma_f32_32x32x16_bf16(
                    afr[mf], wc0, acc[mf][0], 0, 0, 0);
                acc[mf][1] = __builtin_amdgcn_mfma_f32_32x32x16_bf16(
                    afr[mf], wc1, acc[mf][1], 0, 0, 0);
            }
            #pragma unroll
            for (int mf = 0; mf < MF32; ++mf)
                afr[mf] = *(const bf16x8*)(aR + (toff + MFR * mf) * 8 + 2 * SLAB);
            #pragma unroll
            for (int mf = 0; mf < MF32; ++mf) {
                acc[mf][0] = __builtin_amdgcn_mfma_f32_32x32x16_bf16(
                    afr[mf], wc2, acc[mf][0], 0, 0, 0);
                acc[mf][1] = __builtin_amdgcn_mfma_f32_32x32x16_bf16(
                    afr[mf], wc3, acc[mf][1], 0, 0, 0);
            }
            __builtin_amdgcn_s_setprio(0);
            wc0 = wn0; wc1 = wn1; wc2 = wn2; wc3 = wn3;
        }
        wsg += (size_t)TAPS * 16384;
        if ((g & 1) && g < 15) {                 // A chunk boundary (7x)
            __builtin_amdgcn_s_barrier();
            const int chn = (g + 1) >> 1;
            #pragma unroll 1
            for (int q = wv; q < 8 * JC; q += 8) {
                int c8 = q / JC, j = q - c8 * JC;
                gld_lds16(gAh + ((size_t)((chn * 8 + c8) * PLANE) + j * 64) * 8,
                          &As_l[c8 * SLAB + j * 512]);
            }
            asm volatile("s_waitcnt vmcnt(0)" ::: "memory");
            __builtin_amdgcn_s_barrier();
        }
    }
    asm volatile("s_waitcnt vmcnt(0)" ::: "memory");

    // epilogue: y = relu(max4(conv)*sc + (bias*sc + sh)), fused 2x2 pool.
    // C/D 32x32: col = lane&31, row = (r&3) + 8*(r>>2) + 4*(lane>>5)
    #pragma unroll
    for (int nf = 0; nf < 2; ++nf) {
        const int oc = n0 + wn * 64 + nf * 32 + l31;
        const float scv = bnsc[oc], shv = bnsh[oc], bi = bias[oc];
        const float shh = fmaf(bi, scv, shv);
        #pragma unroll
        for (int mf = 0; mf < MF32; ++mf) {
            #pragma unroll
            for (int q = 0; q < 4; ++q) {
                if (!POOL2E) {
                    // quad {r0,r0+1,r0+4,r0+5}: w-pair (+1 row) x h-pair (+8)
                    const int r0 = (q & 1) * 2 + (q >> 1) * 8;   // 0,2,8,10
                    float mx = fmaxf(
                        fmaxf(acc[mf][nf][r0], acc[mf][nf][r0 + 1]),
                        fmaxf(acc[mf][nf][r0 + 4], acc[mf][nf][r0 + 5]));
                    float v = fmaxf(fmaf(mx, scv, shh), 0.f);
                    const int row0 = (r0 & 3) + 8 * (r0 >> 2) + 4 * kgrp;
                    const int pos = wm * MF32 * 32 + mf * 32 + row0;
                    const int h = h0 + (pos >> LOG_OW);
                    const int w = pos & (OW - 1);
                    const int prow = (2 + (h >> 1)) * 4 + (w >> 1);
                    u16* o = (u16*)outp;
                    o[(((size_t)(b * 64 + (oc >> 3))) * 2064 + prow) * 8 +
                      (oc & 7)] = f2bf(v);
                } else {
                    // quad {r0..r0+3}: 4 consecutive positions (h-pair x w-pair)
                    const int r0 = q * 4;
                    float mx = fmaxf(
                        fmaxf(acc[mf][nf][r0], acc[mf][nf][r0 + 1]),
                        fmaxf(acc[mf][nf][r0 + 2], acc[mf][nf][r0 + 3]));
                    float v = fmaxf(fmaf(mx, scv, shh), 0.f);
                    const int row0 = 8 * (r0 >> 2) + 4 * kgrp;
                    const int pos = wm * 32 + row0;
                    const int pout = (h0 + (pos >> 1)) >> 1;
                    float* o = (float*)outp;
                    o[((size_t)(b * 512 + oc)) * 256 + pout] = v;
                }
            }
        }
    }
}

// ---------------- launch ----------------
extern "C" void kernel_launch(void* const* d_in, const int* in_sizes, int n_in,
                              void* d_out, int out_size, void* d_ws, size_t ws_size,
                              hipStream_t stream) {
    const float* x  = (const float*)d_in[0];
    const float* w1 = (const float*)d_in[1];
    const float* b1 = (const float*)d_in[2];
    const float* g1 = (const float*)d_in[3];
    const float* be1 = (const float*)d_in[4];
    const float* m1 = (const float*)d_in[5];
    const float* v1 = (const float*)d_in[6];
    const float* w2 = (const float*)d_in[7];
    const float* b2 = (const float*)d_in[8];
    const float* g2 = (const float*)d_in[9];
    const float* be2 = (const float*)d_in[10];
    const float* m2 = (const float*)d_in[11];
    const float* v2 = (const float*)d_in[12];
    float* out = (float*)d_out;

    char* ws = (char*)d_ws;
    u16* gathered = (u16*)(ws);                    // 101,056,512 B
    u16* w1t      = (u16*)(ws + 101056512);        // 13,107,200 B
    u16* w2t      = (u16*)(ws + 114163712);        //  7,864,320 B
    float* bn1s   = (float*)(ws + 122028032);
    float* bn1t   = bn1s + 512;
    float* bn2s   = bn1s + 1024;
    float* bn2t   = bn1s + 1536;
    u16* pooled1  = (u16*)(ws + 122036224);        // 16,908,288 B

    prep_w1<<<25600, 256, 0, stream>>>(w1, w1t);
    prep_w2<<<15360, 256, 0, stream>>>(w2, w2t);
    prep_bn<<<2, 256, 0, stream>>>(g1, be1, m1, v1, bn1s, bn1t);
    prep_bn<<<2, 256, 0, stream>>>(g2, be2, m2, v2, bn2s, bn2t);
    zero_pads<<<128, 256, 0, stream>>>(gathered, pooled1);
    gather_topk<<<8192, 256, 0, stream>>>(x, gathered);

    // conv1+pool1: 256pos x 256oc tile, TH=32, ARP=448, PLANE=12336
    conv_fused<12, 3, 5, 5, 32, 32, 4, 448, 12336, 64, false>
        <<<512, 512, 0, stream>>>(gathered, w1t, b1, bn1s, bn1t, pooled1);
    // conv2+pool2: 64pos x 256oc tile, TH=32, ARP=192, PLANE=2064 -> d_out
    conv_fused<4, 1, 5, 3, 32, 16, 1, 192, 2064, 32, true>
        <<<256, 512, 0, stream>>>(pooled1, w2t, b2, bn2s, bn2t, out);
}